// Round 4
// baseline (647.058 us; speedup 1.0000x reference)
//
#include <hip/hip_runtime.h>

typedef __attribute__((ext_vector_type(8))) short short8;
typedef __attribute__((ext_vector_type(8))) unsigned short ushort8;
typedef __attribute__((ext_vector_type(4))) float f32x4;

#define B_   32
#define L_   8192
#define IN_  512
#define HID_ 512
#define D3_  128

static __device__ __forceinline__ short f2bf(float f) {
    return __builtin_bit_cast(short, (__bf16)f);
}
static __device__ __forceinline__ unsigned short f2bfu(float f) {
    return __builtin_bit_cast(unsigned short, (__bf16)f);
}

// ---- prep: Wh (f32, D3 x HID) -> bf16 bits in ws ----
__global__ void prep_whb(const float* __restrict__ wh, unsigned short* __restrict__ whb) {
    int i = (blockIdx.x * 256 + threadIdx.x) * 4;   // 65536 elems / 4
    float4 f = *(const float4*)(wh + i);
    whb[i + 0] = f2bfu(f.x);
    whb[i + 1] = f2bfu(f.y);
    whb[i + 2] = f2bfu(f.z);
    whb[i + 3] = f2bfu(f.w);
}

// ---- prep: qpb[b][d] = inputs[b] . Wi[d] + bi[d] + bh[d]  (fp32) ----
__global__ void prep_qpb(const float* __restrict__ inputs, const float* __restrict__ Wi,
                         const float* __restrict__ bi, const float* __restrict__ bh,
                         float* __restrict__ qpb) {
    int b = blockIdx.x;
    int d = threadIdx.x;                 // 128 threads
    float acc = bi[d] + bh[d];
    const float* xr = inputs + b * IN_;
    const float* wr = Wi + d * IN_;
    #pragma unroll 4
    for (int i = 0; i < IN_; i += 4) {
        float4 x = *(const float4*)(xr + i);
        float4 w = *(const float4*)(wr + i);
        acc += x.x * w.x + x.y * w.y + x.z * w.z + x.w * w.w;
    }
    qpb[b * D3_ + d] = acc;
}

// ---- main ----
// 1024 threads = 16 waves/CU (4/SIMD -- 2x R3's latency hiding).
// Each wave: 16 context rows x ALL 128 d3-cols (acc = 32 VGPR), so every
// context line is issued exactly once (no h-pair duplicate issue), no psum
// LDS combine, ZERO barriers in the main loop. Depth-3 register ring with
// static %3 indices (full unroll -> compile-time, rule #20 safe) keeps ~4
// loads/wave in flight -> 64 KB/CU outstanding >> 9 KB Little's-law need.
// Next tile's first two K-steps are issued before the epilogue so the
// exp/shfl reduce hides their latency. Live regs ~95 < the 128 cap.
__global__ __launch_bounds__(1024) void attn_main(
    const float* __restrict__ ctx, const unsigned short* __restrict__ whb,
    const float* __restrict__ qpb, const float* __restrict__ V,
    float* __restrict__ out)
{
    __shared__ unsigned short whs[D3_ * HID_];   // 128 KiB

    const int tid = threadIdx.x;

    // stage Wh^bf16 into LDS, swizzled: 16B slot s of col c stored at s ^ (c&7)
    #pragma unroll
    for (int p = 0; p < 8; ++p) {
        int m = p * 1024 + tid;          // 16B-chunk id: col = m>>6, slot = m&63
        int c = m >> 6;
        int s = m & 63;
        ushort8 v = *(const ushort8*)(whb + (size_t)m * 8);
        *(ushort8*)((char*)whs + c * 1024 + (((s ^ (c & 7)) << 4))) = v;
    }
    __syncthreads();

    const int lane = tid & 63;
    const int w    = tid >> 6;           // wave 0..15, owns 16 rows per tile
    const int cb   = lane & 15;          // A-row / C-col index
    const int g    = lane >> 4;          // k-group 0..3
    const int sw   = cb & 7;             // swizzle key
    const char* bbase = (const char*)whs + cb * 1024;

    const int b = blockIdx.x >> 3;       // 8 blocks per batch item (1024 rows each)

    float vv[8], qv[8];
    #pragma unroll
    for (int nt = 0; nt < 8; ++nt) {
        vv[nt] = V[nt * 16 + cb];
        qv[nt] = qpb[b * D3_ + nt * 16 + cb];
    }

    // this lane's stream: row (base + cb), 8 floats starting at g*8, step 32/kk
    const float* pT = ctx + ((size_t)blockIdx.x * 1024 + w * 16 + cb) * (size_t)HID_ + g * 8;

    float4 buf[3][2];
    buf[0][0] = *(const float4*)(pT);      buf[0][1] = *(const float4*)(pT + 4);
    buf[1][0] = *(const float4*)(pT + 32); buf[1][1] = *(const float4*)(pT + 36);

    for (int t = 0; t < 4; ++t) {          // 4 tiles of 256 rows per block
        f32x4 acc[8];
        #pragma unroll
        for (int nt = 0; nt < 8; ++nt) acc[nt] = (f32x4){0.f, 0.f, 0.f, 0.f};

        #pragma unroll
        for (int kk = 0; kk < 16; ++kk) {
            if (kk < 14) {                 // keep ring 2 steps ahead
                buf[(kk + 2) % 3][0] = *(const float4*)(pT + (kk + 2) * 32);
                buf[(kk + 2) % 3][1] = *(const float4*)(pT + (kk + 2) * 32 + 4);
            }
            const float4 c0 = buf[kk % 3][0];
            const float4 c1 = buf[kk % 3][1];
            short8 aA;
            aA[0] = f2bf(c0.x); aA[1] = f2bf(c0.y); aA[2] = f2bf(c0.z); aA[3] = f2bf(c0.w);
            aA[4] = f2bf(c1.x); aA[5] = f2bf(c1.y); aA[6] = f2bf(c1.z); aA[7] = f2bf(c1.w);

            const int off = (((kk * 4 + g) ^ sw) << 4);
            #pragma unroll
            for (int nt = 0; nt < 8; ++nt) {
                const short8 bb = *(const short8*)(bbase + nt * 16384 + off);
                acc[nt] = __builtin_amdgcn_mfma_f32_16x16x32_bf16(aA, bb, acc[nt], 0, 0, 0);
            }
        }

        pT += (size_t)256 * HID_;          // advance to next 256-row tile
        if (t < 3) {                       // issue next tile's first 2 K-steps NOW;
            buf[0][0] = *(const float4*)(pT);      // epilogue hides their latency
            buf[0][1] = *(const float4*)(pT + 4);
            buf[1][0] = *(const float4*)(pT + 32);
            buf[1][1] = *(const float4*)(pT + 36);
        }

        // epilogue: tanh(acc + q) . V, reduce over the 16 cb lanes
        float s0 = 0.f, s1 = 0.f, s2 = 0.f, s3 = 0.f;
        #pragma unroll
        for (int nt = 0; nt < 8; ++nt) {
            const float q = qv[nt], vn = vv[nt];
            s0 += (1.f - 2.f / (__expf(2.f * (acc[nt][0] + q)) + 1.f)) * vn;
            s1 += (1.f - 2.f / (__expf(2.f * (acc[nt][1] + q)) + 1.f)) * vn;
            s2 += (1.f - 2.f / (__expf(2.f * (acc[nt][2] + q)) + 1.f)) * vn;
            s3 += (1.f - 2.f / (__expf(2.f * (acc[nt][3] + q)) + 1.f)) * vn;
        }
        #pragma unroll
        for (int m = 1; m < 16; m <<= 1) {
            s0 += __shfl_xor(s0, m, 64);
            s1 += __shfl_xor(s1, m, 64);
            s2 += __shfl_xor(s2, m, 64);
            s3 += __shfl_xor(s3, m, 64);
        }
        if (cb == 0) {
            const size_t row0 = (size_t)blockIdx.x * 1024 + (size_t)t * 256 + w * 16;
            const size_t off_ = row0 + (size_t)g * 4;
            *(float4*)(out + off_) = make_float4(s0, s1, s2, s3);
            *(float4*)(out + (size_t)B_ * L_ + off_) = make_float4(1.f, 1.f, 1.f, 1.f);
        }
    }
}

extern "C" void kernel_launch(void* const* d_in, const int* in_sizes, int n_in,
                              void* d_out, int out_size, void* d_ws, size_t ws_size,
                              hipStream_t stream) {
    const float* inputs  = (const float*)d_in[0];   // (32, 512)
    const float* context = (const float*)d_in[1];   // (32, 8192, 512)
    const float* Wi      = (const float*)d_in[2];   // (128, 512)
    const float* bi      = (const float*)d_in[3];   // (128,)
    const float* Wh      = (const float*)d_in[4];   // (128, 512)
    const float* bh      = (const float*)d_in[5];   // (128,)
    const float* V       = (const float*)d_in[6];   // (128,)
    float* out = (float*)d_out;                     // [att_row 262144][att 262144]

    unsigned short* whb = (unsigned short*)d_ws;                   // 128 KiB
    float* qpb = (float*)((char*)d_ws + (size_t)D3_ * HID_ * 2);   // 16 KiB

    prep_whb<<<64, 256, 0, stream>>>(Wh, whb);
    prep_qpb<<<B_, D3_, 0, stream>>>(inputs, Wi, bi, bh, qpb);
    attn_main<<<256, 1024, 0, stream>>>(context, whb, qpb, V, out);
}

// Round 5
// 498.952 us; speedup vs baseline: 1.2968x; 1.2968x over previous
//
#include <hip/hip_runtime.h>

typedef __attribute__((ext_vector_type(8))) short short8;
typedef __attribute__((ext_vector_type(8))) unsigned short ushort8;
typedef __attribute__((ext_vector_type(4))) float f32x4;

#define B_   32
#define L_   8192
#define IN_  512
#define HID_ 512
#define D3_  128

static __device__ __forceinline__ short f2bf(float f) {
    return __builtin_bit_cast(short, (__bf16)f);
}
static __device__ __forceinline__ unsigned short f2bfu(float f) {
    return __builtin_bit_cast(unsigned short, (__bf16)f);
}

// ---- prep: Wh (f32, D3 x HID) -> bf16 bits in ws ----
__global__ void prep_whb(const float* __restrict__ wh, unsigned short* __restrict__ whb) {
    int i = (blockIdx.x * 256 + threadIdx.x) * 4;   // 65536 elems / 4
    float4 f = *(const float4*)(wh + i);
    whb[i + 0] = f2bfu(f.x);
    whb[i + 1] = f2bfu(f.y);
    whb[i + 2] = f2bfu(f.z);
    whb[i + 3] = f2bfu(f.w);
}

// ---- prep: qpb[b][d] = inputs[b] . Wi[d] + bi[d] + bh[d]  (fp32) ----
__global__ void prep_qpb(const float* __restrict__ inputs, const float* __restrict__ Wi,
                         const float* __restrict__ bi, const float* __restrict__ bh,
                         float* __restrict__ qpb) {
    int b = blockIdx.x;
    int d = threadIdx.x;                 // 128 threads
    float acc = bi[d] + bh[d];
    const float* xr = inputs + b * IN_;
    const float* wr = Wi + d * IN_;
    #pragma unroll 4
    for (int i = 0; i < IN_; i += 4) {
        float4 x = *(const float4*)(xr + i);
        float4 w = *(const float4*)(wr + i);
        acc += x.x * w.x + x.y * w.y + x.z * w.z + x.w * w.w;
    }
    qpb[b * D3_ + d] = acc;
}

// ---- main ----
// 512 threads = 8 waves (the 512-thread config empirically gets a 128-VGPR
// cap with NO spill; 1024 threads capped at 64 and spilled 500 MB in R4).
// Each wave: 16 rows x ALL 128 d3-cols (acc = 32 VGPR). No column split ->
// each context line issued once, no psum LDS combine, zero barriers in the
// main loop. Depth-4 register ring (named R0..R3, textual macros -- lambdas
// caused SROA spills in R1/R2) satisfies per-wave Little's law:
// period ~200 cyc x depth 4 ~ 900-cyc HBM latency. The ring is refilled
// across the tile boundary so the tanh/shfl epilogue overlaps the next
// tile's first 4 K-steps.
#define LOADK(RA, RB, P, KK) \
    RA = *(const float4*)((P) + (KK) * 32); \
    RB = *(const float4*)((P) + (KK) * 32 + 4);

#define STEPK(RA, RB, KK) { \
    short8 aA; \
    aA[0] = f2bf(RA.x); aA[1] = f2bf(RA.y); aA[2] = f2bf(RA.z); aA[3] = f2bf(RA.w); \
    aA[4] = f2bf(RB.x); aA[5] = f2bf(RB.y); aA[6] = f2bf(RB.z); aA[7] = f2bf(RB.w); \
    const int o_ = ((((KK) * 4 + g) ^ sw) << 4); \
    _Pragma("unroll") \
    for (int nt = 0; nt < 8; ++nt) { \
        const short8 bb = *(const short8*)(bbase + nt * 16384 + o_); \
        acc[nt] = __builtin_amdgcn_mfma_f32_16x16x32_bf16(aA, bb, acc[nt], 0, 0, 0); \
    } }

__global__ __launch_bounds__(512) void attn_main(
    const float* __restrict__ ctx, const unsigned short* __restrict__ whb,
    const float* __restrict__ qpb, const float* __restrict__ V,
    float* __restrict__ out)
{
    __shared__ unsigned short whs[D3_ * HID_];   // 128 KiB

    const int tid = threadIdx.x;

    // stage Wh^bf16 into LDS, swizzled: 16B slot s of col c stored at s ^ (c&7)
    #pragma unroll
    for (int p = 0; p < 16; ++p) {
        int m = p * 512 + tid;           // 16B-chunk id: col = m>>6, slot = m&63
        int c = m >> 6;
        int s = m & 63;
        ushort8 v = *(const ushort8*)(whb + (size_t)m * 8);
        *(ushort8*)((char*)whs + c * 1024 + (((s ^ (c & 7)) << 4))) = v;
    }
    __syncthreads();

    const int lane = tid & 63;
    const int w    = tid >> 6;           // wave 0..7, owns 16 rows per tile
    const int cb   = lane & 15;          // A-row / C-col index
    const int g    = lane >> 4;          // k-group 0..3
    const int sw   = cb & 7;             // swizzle key
    const char* bbase = (const char*)whs + cb * 1024;

    const int b = blockIdx.x >> 3;       // 1024 rows per block, 8 blocks per batch

    float vv[8], qv[8];
    #pragma unroll
    for (int nt = 0; nt < 8; ++nt) {
        vv[nt] = V[nt * 16 + cb];
        qv[nt] = qpb[b * D3_ + nt * 16 + cb];
    }

    const float* pT = ctx + ((size_t)blockIdx.x * 1024 + w * 16 + cb) * (size_t)HID_ + g * 8;

    float4 R0a, R0b, R1a, R1b, R2a, R2b, R3a, R3b;
    LOADK(R0a, R0b, pT, 0)
    LOADK(R1a, R1b, pT, 1)
    LOADK(R2a, R2b, pT, 2)
    LOADK(R3a, R3b, pT, 3)

    #pragma unroll 1
    for (int t = 0; t < 8; ++t) {        // 8 tiles of 128 rows per block
        f32x4 acc[8];
        #pragma unroll
        for (int nt = 0; nt < 8; ++nt) acc[nt] = (f32x4){0.f, 0.f, 0.f, 0.f};

        STEPK(R0a, R0b, 0)   LOADK(R0a, R0b, pT, 4)
        STEPK(R1a, R1b, 1)   LOADK(R1a, R1b, pT, 5)
        STEPK(R2a, R2b, 2)   LOADK(R2a, R2b, pT, 6)
        STEPK(R3a, R3b, 3)   LOADK(R3a, R3b, pT, 7)
        STEPK(R0a, R0b, 4)   LOADK(R0a, R0b, pT, 8)
        STEPK(R1a, R1b, 5)   LOADK(R1a, R1b, pT, 9)
        STEPK(R2a, R2b, 6)   LOADK(R2a, R2b, pT, 10)
        STEPK(R3a, R3b, 7)   LOADK(R3a, R3b, pT, 11)
        STEPK(R0a, R0b, 8)   LOADK(R0a, R0b, pT, 12)
        STEPK(R1a, R1b, 9)   LOADK(R1a, R1b, pT, 13)
        STEPK(R2a, R2b, 10)  LOADK(R2a, R2b, pT, 14)
        STEPK(R3a, R3b, 11)  LOADK(R3a, R3b, pT, 15)

        const float* pN = pT + (size_t)128 * HID_;
        STEPK(R0a, R0b, 12)
        STEPK(R1a, R1b, 13)
        STEPK(R2a, R2b, 14)
        STEPK(R3a, R3b, 15)
        if (t < 7) {                     // refill ring from next tile; epilogue
            LOADK(R0a, R0b, pN, 0)       // below hides these loads' latency
            LOADK(R1a, R1b, pN, 1)
            LOADK(R2a, R2b, pN, 2)
            LOADK(R3a, R3b, pN, 3)
        }

        // epilogue: tanh(acc + q) . V, reduce over the 16 cb lanes
        float s0 = 0.f, s1 = 0.f, s2 = 0.f, s3 = 0.f;
        #pragma unroll
        for (int nt = 0; nt < 8; ++nt) {
            const float q = qv[nt], vn = vv[nt];
            s0 += (1.f - 2.f / (__expf(2.f * (acc[nt][0] + q)) + 1.f)) * vn;
            s1 += (1.f - 2.f / (__expf(2.f * (acc[nt][1] + q)) + 1.f)) * vn;
            s2 += (1.f - 2.f / (__expf(2.f * (acc[nt][2] + q)) + 1.f)) * vn;
            s3 += (1.f - 2.f / (__expf(2.f * (acc[nt][3] + q)) + 1.f)) * vn;
        }
        #pragma unroll
        for (int m = 1; m < 16; m <<= 1) {
            s0 += __shfl_xor(s0, m, 64);
            s1 += __shfl_xor(s1, m, 64);
            s2 += __shfl_xor(s2, m, 64);
            s3 += __shfl_xor(s3, m, 64);
        }
        if (cb == 0) {
            const size_t row0 = (size_t)blockIdx.x * 1024 + (size_t)t * 128 + w * 16;
            const size_t off_ = row0 + (size_t)g * 4;
            *(float4*)(out + off_) = make_float4(s0, s1, s2, s3);
            *(float4*)(out + (size_t)B_ * L_ + off_) = make_float4(1.f, 1.f, 1.f, 1.f);
        }
        pT = pN;
    }
}

extern "C" void kernel_launch(void* const* d_in, const int* in_sizes, int n_in,
                              void* d_out, int out_size, void* d_ws, size_t ws_size,
                              hipStream_t stream) {
    const float* inputs  = (const float*)d_in[0];   // (32, 512)
    const float* context = (const float*)d_in[1];   // (32, 8192, 512)
    const float* Wi      = (const float*)d_in[2];   // (128, 512)
    const float* bi      = (const float*)d_in[3];   // (128,)
    const float* Wh      = (const float*)d_in[4];   // (128, 512)
    const float* bh      = (const float*)d_in[5];   // (128,)
    const float* V       = (const float*)d_in[6];   // (128,)
    float* out = (float*)d_out;                     // [att_row 262144][att 262144]

    unsigned short* whb = (unsigned short*)d_ws;                   // 128 KiB
    float* qpb = (float*)((char*)d_ws + (size_t)D3_ * HID_ * 2);   // 16 KiB

    prep_whb<<<64, 256, 0, stream>>>(Wh, whb);
    prep_qpb<<<B_, D3_, 0, stream>>>(inputs, Wi, bi, bh, qpb);
    attn_main<<<256, 512, 0, stream>>>(context, whb, qpb, V, out);
}

// Round 6
// 127.426 us; speedup vs baseline: 5.0779x; 3.9156x over previous
//
#include <hip/hip_runtime.h>

typedef __attribute__((ext_vector_type(8))) short short8;
typedef __attribute__((ext_vector_type(8))) unsigned short ushort8;
typedef __attribute__((ext_vector_type(4))) float f32x4;

#define B_   32
#define L_   8192
#define IN_  512
#define HID_ 512
#define D3_  128

static __device__ __forceinline__ short f2bf(float f) {
    return __builtin_bit_cast(short, (__bf16)f);
}
static __device__ __forceinline__ unsigned short f2bfu(float f) {
    return __builtin_bit_cast(unsigned short, (__bf16)f);
}

// async global->LDS, 16B per lane, dest = wave-uniform base + lane*16
static __device__ __forceinline__ void gload_lds16(const void* g, void* l) {
    __builtin_amdgcn_global_load_lds(
        (const __attribute__((address_space(1))) unsigned int*)g,
        (__attribute__((address_space(3))) unsigned int*)l, 16, 0, 0);
}

// ---- prep: Wh (f32, D3 x HID) -> bf16 bits in ws ----
__global__ void prep_whb(const float* __restrict__ wh, unsigned short* __restrict__ whb) {
    int i = (blockIdx.x * 256 + threadIdx.x) * 4;   // 65536 elems / 4
    float4 f = *(const float4*)(wh + i);
    whb[i + 0] = f2bfu(f.x);
    whb[i + 1] = f2bfu(f.y);
    whb[i + 2] = f2bfu(f.z);
    whb[i + 3] = f2bfu(f.w);
}

// ---- prep: qpb[b][d] = inputs[b] . Wi[d] + bi[d] + bh[d]  (fp32) ----
__global__ void prep_qpb(const float* __restrict__ inputs, const float* __restrict__ Wi,
                         const float* __restrict__ bi, const float* __restrict__ bh,
                         float* __restrict__ qpb) {
    int b = blockIdx.x;
    int d = threadIdx.x;                 // 128 threads
    float acc = bi[d] + bh[d];
    const float* xr = inputs + b * IN_;
    const float* wr = Wi + d * IN_;
    #pragma unroll 4
    for (int i = 0; i < IN_; i += 4) {
        float4 x = *(const float4*)(xr + i);
        float4 w = *(const float4*)(wr + i);
        acc += x.x * w.x + x.y * w.y + x.z * w.z + x.w * w.w;
    }
    qpb[b * D3_ + d] = acc;
}

// ---- main ----
// R2/R4/R5 all spilled: deep REGISTER prefetch + 32-reg acc does not fit the
// empirical 128-VGPR cap. R6 moves all prefetch state to LDS via async
// global_load_lds (in-flight bytes cost ZERO VGPRs):
//   LDS = Wh^bf16 128 KiB + context dbuf 2x16 KiB = 160 KiB (full CU pool).
// Each of 8 waves owns 16 rows x 128 cols; per K-chunk (32 f32/row = one
// MFMA K-step) the wave DMAs its own 2 KB slice with 2 global_load_lds
// issues into a wave-PRIVATE LDS region -> no cross-wave deps, no barriers,
// counted s_waitcnt vmcnt(2) keeps one chunk always in flight.
// Swizzle (rule #21, both-sides): linear LDS dest; global SOURCE slot
// pre-swizzled s^ (row&7); READ uses the same XOR -> bank-even A-reads.
__global__ __launch_bounds__(512) void attn_main(
    const float* __restrict__ ctx, const unsigned short* __restrict__ whb,
    const float* __restrict__ qpb, const float* __restrict__ V,
    float* __restrict__ out)
{
    __shared__ unsigned short whs[D3_ * HID_];   // 128 KiB
    __shared__ float cbuf[2][4096];              // 32 KiB: 2 bufs x 8 waves x 2 KB

    const int tid = threadIdx.x;

    // stage Wh^bf16 into LDS, swizzled: 16B slot s of col c stored at s ^ (c&7)
    #pragma unroll
    for (int p = 0; p < 16; ++p) {
        int m = p * 512 + tid;           // 16B-chunk id: col = m>>6, slot = m&63
        int c = m >> 6;
        int s = m & 63;
        ushort8 v = *(const ushort8*)(whb + (size_t)m * 8);
        *(ushort8*)((char*)whs + c * 1024 + (((s ^ (c & 7)) << 4))) = v;
    }
    __syncthreads();

    const int lane = tid & 63;
    const int w    = tid >> 6;           // wave 0..7, owns 16 rows per tile
    const int cb   = lane & 15;          // A-row / C-col index
    const int g    = lane >> 4;          // k-group 0..3
    const int sw   = cb & 7;             // whs swizzle key
    const char* bbase = (const char*)whs + cb * 1024;

    // DMA lane constants
    const int ri  = lane >> 3;           // row-in-8 (0..7)
    const int sl  = lane & 7;            // linear 16B slot this lane FILLS
    const int ssl = sl ^ ri;             // swizzled slot this lane FETCHES
    const float* gbase = ctx + ((size_t)blockIdx.x * 1024 + w * 16 + ri) * (size_t)HID_ + ssl * 4;
    char* lbase = (char*)cbuf + w * 2048 + lane * 16;   // wave-private slice

    // A-read addresses (constant per lane; only parity toggles)
    const char* abase = (char*)cbuf + w * 2048 + (cb >> 3) * 1024 + (cb & 7) * 128;
    const int aoff0 = (((2 * g)     ^ (cb & 7)) << 4);
    const int aoff1 = (((2 * g + 1) ^ (cb & 7)) << 4);

    const int b = blockIdx.x >> 3;       // 1024 rows per block, 8 blocks per batch

    float vv[8], qv[8];
    #pragma unroll
    for (int nt = 0; nt < 8; ++nt) {
        vv[nt] = V[nt * 16 + cb];
        qv[nt] = qpb[b * D3_ + nt * 16 + cb];
    }

#define STAGE(CC) { \
    const float* g0_ = gbase + (size_t)((CC) >> 4) * (128 * HID_) + ((CC) & 15) * 32; \
    char* l0_ = lbase + (((CC) & 1) ? 16384 : 0); \
    gload_lds16(g0_, l0_); \
    gload_lds16(g0_ + 8 * HID_, l0_ + 1024); \
}

    STAGE(0)
    STAGE(1)

    #pragma unroll 1
    for (int t = 0; t < 8; ++t) {        // 8 tiles of 128 rows
        f32x4 acc[8];
        #pragma unroll
        for (int nt = 0; nt < 8; ++nt) acc[nt] = (f32x4){0.f, 0.f, 0.f, 0.f};

        #pragma unroll
        for (int kk = 0; kk < 16; ++kk) {
            const int c = t * 16 + kk;
            if (c < 127) asm volatile("s_waitcnt vmcnt(2)" ::: "memory");
            else         asm volatile("s_waitcnt vmcnt(0)" ::: "memory");

            const char* ab = abase + ((c & 1) ? 16384 : 0);
            const f32x4 a0 = *(const f32x4*)(ab + aoff0);
            const f32x4 a1 = *(const f32x4*)(ab + aoff1);
            short8 aA;
            aA[0] = f2bf(a0[0]); aA[1] = f2bf(a0[1]); aA[2] = f2bf(a0[2]); aA[3] = f2bf(a0[3]);
            aA[4] = f2bf(a1[0]); aA[5] = f2bf(a1[1]); aA[6] = f2bf(a1[2]); aA[7] = f2bf(a1[3]);

            const int o_ = (((kk * 4 + g) ^ sw) << 4);
            #pragma unroll
            for (int nt = 0; nt < 8; ++nt) {
                const short8 bb = *(const short8*)(bbase + nt * 16384 + o_);
                acc[nt] = __builtin_amdgcn_mfma_f32_16x16x32_bf16(aA, bb, acc[nt], 0, 0, 0);
            }
            // A/B LDS reads must complete before DMA may overwrite this buffer
            asm volatile("s_waitcnt lgkmcnt(0)" ::: "memory");

            if (kk == 15) {
                // epilogue: tanh(acc + q) . V, reduce over the 16 cb lanes
                float s0 = 0.f, s1 = 0.f, s2 = 0.f, s3 = 0.f;
                #pragma unroll
                for (int nt = 0; nt < 8; ++nt) {
                    const float q = qv[nt], vn = vv[nt];
                    s0 += (1.f - 2.f / (__expf(2.f * (acc[nt][0] + q)) + 1.f)) * vn;
                    s1 += (1.f - 2.f / (__expf(2.f * (acc[nt][1] + q)) + 1.f)) * vn;
                    s2 += (1.f - 2.f / (__expf(2.f * (acc[nt][2] + q)) + 1.f)) * vn;
                    s3 += (1.f - 2.f / (__expf(2.f * (acc[nt][3] + q)) + 1.f)) * vn;
                }
                #pragma unroll
                for (int m = 1; m < 16; m <<= 1) {
                    s0 += __shfl_xor(s0, m, 64);
                    s1 += __shfl_xor(s1, m, 64);
                    s2 += __shfl_xor(s2, m, 64);
                    s3 += __shfl_xor(s3, m, 64);
                }
                if (cb == 0) {
                    const size_t row0 = (size_t)blockIdx.x * 1024 + (size_t)t * 128 + w * 16;
                    const size_t off_ = row0 + (size_t)g * 4;
                    *(float4*)(out + off_) = make_float4(s0, s1, s2, s3);
                    *(float4*)(out + (size_t)B_ * L_ + off_) = make_float4(1.f, 1.f, 1.f, 1.f);
                }
            }
            if (c + 2 < 128) STAGE(c + 2)
        }
    }
#undef STAGE
}

extern "C" void kernel_launch(void* const* d_in, const int* in_sizes, int n_in,
                              void* d_out, int out_size, void* d_ws, size_t ws_size,
                              hipStream_t stream) {
    const float* inputs  = (const float*)d_in[0];   // (32, 512)
    const float* context = (const float*)d_in[1];   // (32, 8192, 512)
    const float* Wi      = (const float*)d_in[2];   // (128, 512)
    const float* bi      = (const float*)d_in[3];   // (128,)
    const float* Wh      = (const float*)d_in[4];   // (128, 512)
    const float* bh      = (const float*)d_in[5];   // (128,)
    const float* V       = (const float*)d_in[6];   // (128,)
    float* out = (float*)d_out;                     // [att_row 262144][att 262144]

    unsigned short* whb = (unsigned short*)d_ws;                   // 128 KiB
    float* qpb = (float*)((char*)d_ws + (size_t)D3_ * HID_ * 2);   // 16 KiB

    prep_whb<<<64, 256, 0, stream>>>(Wh, whb);
    prep_qpb<<<B_, D3_, 0, stream>>>(inputs, Wi, bi, bh, qpb);
    attn_main<<<256, 512, 0, stream>>>(context, whb, qpb, V, out);
}